// Round 13
// baseline (255.175 us; speedup 1.0000x reference)
//
#include <hip/hip_runtime.h>
#include <stdint.h>

typedef unsigned short u16;
typedef __bf16 bf16x8 __attribute__((ext_vector_type(8)));
typedef float f32x16 __attribute__((ext_vector_type(16)));

// ---- sizes ----
// x: (32,256,56,56) f32, W: (256,256,3,3) f32, out: (32,256,28,28) f32
#define M_TOTAL    100352          // 32*56*56
#define PLANE_U16  861184L         // one 8-ch plane: 32*58*58 rows * 8 u16
#define WPACK_OFF  55115776L       // xp2 = 32 planes * 861184 * 2B
#define Y_OFF      56295424L       // + 9*256*256*2 = 1179648
#define STATS_OFF  107675648L      // + 32*56*56*256*2 = 51380224

__device__ __forceinline__ u16 f32_bf16(float f) {
  uint32_t u = __float_as_uint(f);
  u += 0x7FFFu + ((u >> 16) & 1u);
  return (u16)(u >> 16);
}
__device__ __forceinline__ float bf16_f32(u16 h) {
  return __uint_as_float(((uint32_t)h) << 16);
}

// ---- binarize + pack W:  wp[((f*32+cg)*256 + co)*8 + e] = sign(W[co][ci][kh][kw])
__global__ void prep_w(const float* __restrict__ W, u16* __restrict__ wp) {
  int idx = blockIdx.x * 256 + threadIdx.x;       // 0..589823
  int e  = idx & 7;
  int co = (idx >> 3) & 255;
  int ks = idx >> 11;                             // f*32 + cg
  int f  = ks >> 5;
  int ci = ((ks & 31) << 3) | e;
  int kh = (f * 11) >> 5;                         // f/3 for f in 0..8
  int kw = f - kh * 3;
  float v = W[((co * 256 + ci) * 3 + kh) * 3 + kw];
  wp[idx] = (u16)(0x3F80u | ((__float_as_uint(v) >> 16) & 0x8000u));
}

// ---- zero only the padded border rows of xp2 (all 32 planes)
__global__ void border_zero(u16* __restrict__ xp2) {
  int idx = blockIdx.x * 256 + threadIdx.x;       // 32n*228p*32g = 233472
  int g = idx & 31;
  int p = (idx >> 5) % 228;
  int n = (idx >> 5) / 228;
  int h, w;
  if (p < 58)       { h = 0;  w = p; }
  else if (p < 116) { h = 57; w = p - 58; }
  else { int q = p - 116; h = 1 + (q >> 1); w = 57 * (q & 1); }
  long r = ((long)n * 58 + h) * 58 + w;
  *(uint4*)(xp2 + g * PLANE_U16 + r * 8) = make_uint4(0, 0, 0, 0);
}

// ---- NCHW f32 -> channel-plane bf16: xp2[c/8][padded row][c&7]  (float4 loads)
__global__ void prep_x(const float* __restrict__ x, u16* __restrict__ xp2) {
  int b = blockIdx.x;                 // (n*56 + h)*4 + cblk
  int cblk = b & 3;
  int nh = b >> 2;
  int h = nh % 56, n = nh / 56;
  __shared__ float tile[64][57];
  int tid = threadIdx.x;
  const float* src = x + (((long)n * 256 + cblk * 64) * 56 + h) * 56;
  // 64 rows x 14 float4 each: idx over 64x16 slots, mask v4 < 14
#pragma unroll
  for (int i = 0; i < 4; ++i) {
    int idx = i * 256 + tid;          // 0..1023
    int c = idx >> 4, v4 = idx & 15;  // c 0..63, v4 0..15 (0..13 valid)
    if (v4 < 14) {
      float4 d = *(const float4*)(src + (long)c * 3136 + v4 * 4);
      tile[c][v4 * 4 + 0] = d.x;
      tile[c][v4 * 4 + 1] = d.y;
      tile[c][v4 * 4 + 2] = d.z;
      tile[c][v4 * 4 + 3] = d.w;
    }
  }
  __syncthreads();
  u16* base = xp2 + (long)(cblk * 8) * PLANE_U16 + (((long)n * 58 + h + 1) * 58 + 1) * 8;
#pragma unroll
  for (int i = 0; i < 2; ++i) {
    int idx = i * 256 + tid;          // 448 items: w(56) x g(8)
    if (idx < 448) {
      int wq = idx >> 3, g = idx & 7;
      union { uint4 u; u16 hx[8]; } d;
#pragma unroll
      for (int e = 0; e < 8; ++e) d.hx[e] = f32_bf16(tile[g * 8 + e][wq]);
      *(uint4*)(base + (long)g * PLANE_U16 + wq * 8) = d.u;
    }
  }
}

// ---- implicit-GEMM conv: LDS-free, barrier-free, manual counted-vmcnt pipeline.
//      4 independent waves/block, wave tile 128x64, A/B double-buffered in regs
//      with refill issued right after consumption (full-MFMA8 age-at-use).
__global__ __launch_bounds__(256, 2) void conv_gemm(
    const u16* __restrict__ xp2, const u16* __restrict__ wp,
    u16* __restrict__ y, float* __restrict__ stats) {
  const int tid = threadIdx.x;
  const int w = tid >> 6, l = tid & 63;
  const int gm = blockIdx.x;                       // 784 M-tiles
  const int l31 = l & 31, lh = l >> 5;

  // per-lane A offsets (u16 units): plane-half lh + padded row (per rb)
  long voffA0, voffA1, voffA2, voffA3;
  {
    long vs[4];
#pragma unroll
    for (int rb = 0; rb < 4; ++rb) {
      int gr = gm * 128 + rb * 32 + l31;
      int n = gr / 3136, rem = gr - n * 3136;
      int hh = rem / 56, wx = rem - hh * 56;
      vs[rb] = (long)lh * PLANE_U16 + (((long)n * 58 + hh) * 58 + wx) * 8;
    }
    voffA0 = vs[0]; voffA1 = vs[1]; voffA2 = vs[2]; voffA3 = vs[3];
  }
  const long voffB = (long)lh * 2048 + ((w << 6) + l31) * 8;

  bf16x8 aC[2][4], aN[2][4], bC[2][2], bN[2][2];   // [kc][rb] / [kc][cb]
  f32x16 acc[4][2] = {};

  // K-half T = f*8 + cc: tap f = T>>3 (row shift), channel chunk cc = T&7
  // planes for half T: cc*4 + kc*2 + lh  (lh folded into voffA)
#define LOADA(T, DST)                                                        \
  {                                                                          \
    const int f_ = (T) >> 3;                                                 \
    const int kh_ = (f_ * 11) >> 5;                                          \
    const int kw_ = f_ - kh_ * 3;                                            \
    const u16* ba = xp2 + (long)((T) & 7) * 4 * PLANE_U16                    \
                    + (kh_ * 58 + kw_) * 8;                                  \
    DST[0][0] = *(const bf16x8*)(ba + voffA0);                               \
    DST[0][1] = *(const bf16x8*)(ba + voffA1);                               \
    DST[0][2] = *(const bf16x8*)(ba + voffA2);                               \
    DST[0][3] = *(const bf16x8*)(ba + voffA3);                               \
    const u16* ba1 = ba + 2 * PLANE_U16;                                     \
    DST[1][0] = *(const bf16x8*)(ba1 + voffA0);                              \
    DST[1][1] = *(const bf16x8*)(ba1 + voffA1);                              \
    DST[1][2] = *(const bf16x8*)(ba1 + voffA2);                              \
    DST[1][3] = *(const bf16x8*)(ba1 + voffA3);                              \
  }
#define LOADB(T, DST)                                                        \
  {                                                                          \
    const u16* bb = wp + (long)((((T) >> 3) << 5) + (((T) & 7) << 2)) * 2048 \
                    + voffB;                                                 \
    DST[0][0] = *(const bf16x8*)(bb);                                        \
    DST[0][1] = *(const bf16x8*)(bb + 256);                                  \
    DST[1][0] = *(const bf16x8*)(bb + 4096);                                 \
    DST[1][1] = *(const bf16x8*)(bb + 4096 + 256);                           \
  }
#define MFMA8(A, B)                                                          \
  {                                                                          \
    _Pragma("unroll")                                                        \
    for (int kc = 0; kc < 2; ++kc)                                           \
      _Pragma("unroll")                                                      \
      for (int rb = 0; rb < 4; ++rb) {                                       \
        acc[rb][0] = __builtin_amdgcn_mfma_f32_32x32x16_bf16(                \
            A[kc][rb], B[kc][0], acc[rb][0], 0, 0, 0);                       \
        acc[rb][1] = __builtin_amdgcn_mfma_f32_32x32x16_bf16(                \
            A[kc][rb], B[kc][1], acc[rb][1], 0, 0, 0);                       \
      }                                                                      \
  }
// force the oldest 12 VMEM (the group about to be consumed); pin MFMA order
#define WAIT12 { asm volatile("s_waitcnt vmcnt(12)" ::: "memory");           \
                 __builtin_amdgcn_sched_barrier(0); }
#define WAIT0  { asm volatile("s_waitcnt vmcnt(0)" ::: "memory");            \
                 __builtin_amdgcn_sched_barrier(0); }

  // prologue: two halves in flight (24 loads)
  LOADA(0, aC); LOADB(0, bC);
  LOADA(1, aN); LOADB(1, bN);

  for (int i = 0; i < 36; ++i) {
    const int h = i * 2;
    // consume group C (half h): it is the oldest 12 outstanding
    WAIT12;
    __builtin_amdgcn_s_setprio(1);
    MFMA8(aC, bC);
    __builtin_amdgcn_s_setprio(0);
    if (h + 2 < 72) { LOADA(h + 2, aC); LOADB(h + 2, bC); }
    // consume group N (half h+1)
    if (h + 2 < 72) WAIT12 else WAIT0;             // force h+1's 12
    __builtin_amdgcn_s_setprio(1);
    MFMA8(aN, bN);
    __builtin_amdgcn_s_setprio(0);
    if (h + 3 < 72) { LOADA(h + 3, aN); LOADB(h + 3, bN); }
  }
#undef LOADA
#undef LOADB
#undef MFMA8
#undef WAIT12
#undef WAIT0

  // ---- per-channel partial sums -> atomics (C col = lane&31)
#pragma unroll
  for (int cb = 0; cb < 2; ++cb) {
    float s = 0.f, q = 0.f;
#pragma unroll
    for (int rb = 0; rb < 4; ++rb)
#pragma unroll
      for (int j = 0; j < 16; ++j) {
        float v = acc[rb][cb][j];
        s += v; q += v * v;
      }
    s += __shfl_xor(s, 32, 64);
    q += __shfl_xor(q, 32, 64);
    if (lh == 0) {
      int col = (w << 6) + cb * 32 + l31;
      atomicAdd(&stats[col], s);
      atomicAdd(&stats[256 + col], q);
    }
  }

  // ---- store y bf16: row = (reg&3) + 8*(reg>>2) + 4*lh, col = lane&31
  const long rbase = (long)gm * 128;
#pragma unroll
  for (int rb = 0; rb < 4; ++rb)
#pragma unroll
    for (int j = 0; j < 16; ++j) {
      long rr = rbase + rb * 32 + (j & 3) + 8 * (j >> 2) + 4 * lh;
      u16* dst = y + rr * 256 + (w << 6) + l31;
      dst[0]  = f32_bf16(acc[rb][0][j]);
      dst[32] = f32_bf16(acc[rb][1][j]);
    }
}

// ---- finalize BN coefficients: scale = gamma*rsqrt(var+eps), shift = beta - mean*scale
__global__ void bn_stats(const float* __restrict__ stats, const float* __restrict__ gamma,
                         const float* __restrict__ beta, float* __restrict__ sc) {
  int c = threadIdx.x;
  const float inv = 1.0f / (float)M_TOTAL;
  float mean = stats[c] * inv;
  float var  = stats[256 + c] * inv - mean * mean;
  float s = gamma[c] * rsqrtf(var + 1e-5f);
  float b = beta[c] - mean * s;
  sc[c] = s;
  sc[256 + c] = b;
}

// ---- fused BN + ReLU + 2x2 maxpool, NHWC bf16 -> NCHW f32 ----
__global__ void bn_pool(const u16* __restrict__ y, const float* __restrict__ sc,
                        float* __restrict__ out) {
  int b = blockIdx.x;                 // n*28 + ho
  int ho = b % 28, n = b / 28;
  __shared__ u16 t[256][113];         // [co][h2*56+wq], pad to break conflicts
  __shared__ float ssc[256], ssb[256];
  int tid = threadIdx.x;
  ssc[tid] = sc[tid];
  ssb[tid] = sc[256 + tid];
  const u16* src = y + (((long)n * 56 + ho * 2) * 56) * 256;
#pragma unroll
  for (int i = 0; i < 14; ++i) {
    int v = i * 256 + tid;            // vec idx over (h2,wq,co/8): 3584 vecs
    int cv = v & 31, hw = v >> 5;     // hw = h2*56+wq in 0..111
    union { uint4 u; u16 h[8]; } d;
    d.u = *(const uint4*)(src + (long)hw * 256 + cv * 8);
#pragma unroll
    for (int e = 0; e < 8; ++e) t[cv * 8 + e][hw] = d.h[e];
  }
  __syncthreads();
  float* dst = out + (long)n * 200704 + ho * 28;   // + co*784 + wo
#pragma unroll
  for (int i = 0; i < 28; ++i) {
    int oidx = i * 256 + tid;         // 0..7167
    int co = oidx / 28, wo = oidx - co * 28;
    float s = ssc[co], bb = ssb[co];
    int w0 = wo * 2;
    float r0 = fmaxf(s * bf16_f32(t[co][w0])      + bb, 0.f);
    float r1 = fmaxf(s * bf16_f32(t[co][w0 + 1])  + bb, 0.f);
    float r2 = fmaxf(s * bf16_f32(t[co][56 + w0]) + bb, 0.f);
    float r3 = fmaxf(s * bf16_f32(t[co][57 + w0]) + bb, 0.f);
    dst[(long)co * 784 + wo] = fmaxf(fmaxf(r0, r1), fmaxf(r2, r3));
  }
}

extern "C" void kernel_launch(void* const* d_in, const int* in_sizes, int n_in,
                              void* d_out, int out_size, void* d_ws, size_t ws_size,
                              hipStream_t stream) {
  const float* x     = (const float*)d_in[0];
  const float* W     = (const float*)d_in[1];
  const float* gamma = (const float*)d_in[2];
  const float* beta  = (const float*)d_in[3];
  float* out = (float*)d_out;
  char* ws = (char*)d_ws;
  u16*  xp2   = (u16*)ws;
  u16*  wp    = (u16*)(ws + WPACK_OFF);
  u16*  yb    = (u16*)(ws + Y_OFF);
  float* stats = (float*)(ws + STATS_OFF);   // sum[256], sumsq[256], scale[256], shift[256]

  hipMemsetAsync(stats, 0, 512 * sizeof(float), stream);
  hipLaunchKernelGGL(border_zero, dim3(912), dim3(256), 0, stream, xp2);
  hipLaunchKernelGGL(prep_w, dim3(2304), dim3(256), 0, stream, W, wp);
  hipLaunchKernelGGL(prep_x, dim3(32 * 56 * 4), dim3(256), 0, stream, x, xp2);
  hipLaunchKernelGGL(conv_gemm, dim3(784), dim3(256), 0, stream, xp2, wp, yb, stats);
  hipLaunchKernelGGL(bn_stats, dim3(1), dim3(256), 0, stream, stats, gamma, beta, stats + 512);
  hipLaunchKernelGGL(bn_pool, dim3(32 * 28), dim3(256), 0, stream, yb, stats + 512, out);
}

// Round 14
// 208.614 us; speedup vs baseline: 1.2232x; 1.2232x over previous
//
#include <hip/hip_runtime.h>
#include <stdint.h>

typedef unsigned short u16;
typedef __bf16 bf16x8 __attribute__((ext_vector_type(8)));
typedef float f32x16 __attribute__((ext_vector_type(16)));

// ---- sizes ----
// x: (32,256,56,56) f32, W: (256,256,3,3) f32, out: (32,256,28,28) f32
#define M_TOTAL    100352          // 32*56*56
#define PLANE_U16  861184L         // one 8-ch plane: 32*58*58 rows * 8 u16
#define WPACK_OFF  55115776L       // xp2 = 32 planes * 861184 * 2B
#define Y_OFF      56295424L       // + 9*256*256*2 = 1179648
#define STATS_OFF  107675648L      // + 32*56*56*256*2 = 51380224

__device__ __forceinline__ u16 f32_bf16(float f) {
  uint32_t u = __float_as_uint(f);
  u += 0x7FFFu + ((u >> 16) & 1u);
  return (u16)(u >> 16);
}
__device__ __forceinline__ float bf16_f32(u16 h) {
  return __uint_as_float(((uint32_t)h) << 16);
}

// ---- binarize + pack W:  wp[((f*32+cg)*256 + co)*8 + e] = sign(W[co][ci][kh][kw])
__global__ void prep_w(const float* __restrict__ W, u16* __restrict__ wp) {
  int idx = blockIdx.x * 256 + threadIdx.x;       // 0..589823
  int e  = idx & 7;
  int co = (idx >> 3) & 255;
  int ks = idx >> 11;                             // f*32 + cg
  int f  = ks >> 5;
  int ci = ((ks & 31) << 3) | e;
  int kh = (f * 11) >> 5;                         // f/3 for f in 0..8
  int kw = f - kh * 3;
  float v = W[((co * 256 + ci) * 3 + kh) * 3 + kw];
  wp[idx] = (u16)(0x3F80u | ((__float_as_uint(v) >> 16) & 0x8000u));
}

// ---- zero only the padded border rows of xp2 (all 32 planes)
__global__ void border_zero(u16* __restrict__ xp2) {
  int idx = blockIdx.x * 256 + threadIdx.x;       // 32n*228p*32g = 233472
  int g = idx & 31;
  int p = (idx >> 5) % 228;
  int n = (idx >> 5) / 228;
  int h, w;
  if (p < 58)       { h = 0;  w = p; }
  else if (p < 116) { h = 57; w = p - 58; }
  else { int q = p - 116; h = 1 + (q >> 1); w = 57 * (q & 1); }
  long r = ((long)n * 58 + h) * 58 + w;
  *(uint4*)(xp2 + g * PLANE_U16 + r * 8) = make_uint4(0, 0, 0, 0);
}

// ---- NCHW f32 -> channel-plane bf16: xp2[c/8][padded row][c&7]  (float4 loads)
__global__ void prep_x(const float* __restrict__ x, u16* __restrict__ xp2) {
  int b = blockIdx.x;                 // (n*56 + h)*4 + cblk
  int cblk = b & 3;
  int nh = b >> 2;
  int h = nh % 56, n = nh / 56;
  __shared__ float tile[64][57];
  int tid = threadIdx.x;
  const float* src = x + (((long)n * 256 + cblk * 64) * 56 + h) * 56;
  // 64 rows x 14 float4 each: idx over 64x16 slots, mask v4 < 14
#pragma unroll
  for (int i = 0; i < 4; ++i) {
    int idx = i * 256 + tid;          // 0..1023
    int c = idx >> 4, v4 = idx & 15;  // c 0..63, v4 0..15 (0..13 valid)
    if (v4 < 14) {
      float4 d = *(const float4*)(src + (long)c * 3136 + v4 * 4);
      tile[c][v4 * 4 + 0] = d.x;
      tile[c][v4 * 4 + 1] = d.y;
      tile[c][v4 * 4 + 2] = d.z;
      tile[c][v4 * 4 + 3] = d.w;
    }
  }
  __syncthreads();
  u16* base = xp2 + (long)(cblk * 8) * PLANE_U16 + (((long)n * 58 + h + 1) * 58 + 1) * 8;
#pragma unroll
  for (int i = 0; i < 2; ++i) {
    int idx = i * 256 + tid;          // 448 items: w(56) x g(8)
    if (idx < 448) {
      int wq = idx >> 3, g = idx & 7;
      union { uint4 u; u16 hx[8]; } d;
#pragma unroll
      for (int e = 0; e < 8; ++e) d.hx[e] = f32_bf16(tile[g * 8 + e][wq]);
      *(uint4*)(base + (long)g * PLANE_U16 + wq * 8) = d.u;
    }
  }
}

// ---- implicit-GEMM conv: LDS-free, barrier-free, compiler-scheduled (R10 proven),
//      K-halves iterated CHANNEL-MAJOR (cc outer, tap f inner) so each cc-group's
//      9 taps re-read the same ~16 KB A-region -> L1-resident. 2 blocks/CU.
__global__ __launch_bounds__(256, 2) void conv_gemm(
    const u16* __restrict__ xp2, const u16* __restrict__ wp,
    u16* __restrict__ y, float* __restrict__ stats) {
  const int tid = threadIdx.x;
  const int w = tid >> 6, l = tid & 63;
  const int gm = blockIdx.x;                       // 784 M-tiles
  const int l31 = l & 31, lh = l >> 5;

  // per-lane A offsets (u16 units): plane-half lh + padded row (per rb)
  long voffA0, voffA1, voffA2, voffA3;
  {
    long vs[4];
#pragma unroll
    for (int rb = 0; rb < 4; ++rb) {
      int gr = gm * 128 + rb * 32 + l31;
      int n = gr / 3136, rem = gr - n * 3136;
      int hh = rem / 56, wx = rem - hh * 56;
      vs[rb] = (long)lh * PLANE_U16 + (((long)n * 58 + hh) * 58 + wx) * 8;
    }
    voffA0 = vs[0]; voffA1 = vs[1]; voffA2 = vs[2]; voffA3 = vs[3];
  }
  const long voffB = (long)lh * 2048 + ((w << 6) + l31) * 8;

  bf16x8 aC[2][4], aN[2][4], bC[2][2], bN[2][2];   // [kc][rb] / [kc][cb]
  f32x16 acc[4][2] = {};

  // K-half coords: channel chunk CC (0..7), tap F (0..8); planes CC*4 + kc*2 + lh
#define LOADA(F, CC, DST)                                                    \
  {                                                                          \
    const int kh_ = ((F) * 11) >> 5;                                         \
    const int kw_ = (F) - kh_ * 3;                                           \
    const u16* ba = xp2 + (long)(CC) * 4 * PLANE_U16                         \
                    + (kh_ * 58 + kw_) * 8;                                  \
    DST[0][0] = *(const bf16x8*)(ba + voffA0);                               \
    DST[0][1] = *(const bf16x8*)(ba + voffA1);                               \
    DST[0][2] = *(const bf16x8*)(ba + voffA2);                               \
    DST[0][3] = *(const bf16x8*)(ba + voffA3);                               \
    const u16* ba1 = ba + 2 * PLANE_U16;                                     \
    DST[1][0] = *(const bf16x8*)(ba1 + voffA0);                              \
    DST[1][1] = *(const bf16x8*)(ba1 + voffA1);                              \
    DST[1][2] = *(const bf16x8*)(ba1 + voffA2);                              \
    DST[1][3] = *(const bf16x8*)(ba1 + voffA3);                              \
  }
#define LOADB(F, CC, DST)                                                    \
  {                                                                          \
    const u16* bb = wp + (long)(((F) << 5) + ((CC) << 2)) * 2048 + voffB;    \
    DST[0][0] = *(const bf16x8*)(bb);                                        \
    DST[0][1] = *(const bf16x8*)(bb + 256);                                  \
    DST[1][0] = *(const bf16x8*)(bb + 4096);                                 \
    DST[1][1] = *(const bf16x8*)(bb + 4096 + 256);                           \
  }
#define MFMA8(A, B)                                                          \
  {                                                                          \
    _Pragma("unroll")                                                        \
    for (int kc = 0; kc < 2; ++kc)                                           \
      _Pragma("unroll")                                                      \
      for (int rb = 0; rb < 4; ++rb) {                                       \
        acc[rb][0] = __builtin_amdgcn_mfma_f32_32x32x16_bf16(                \
            A[kc][rb], B[kc][0], acc[rb][0], 0, 0, 0);                       \
        acc[rb][1] = __builtin_amdgcn_mfma_f32_32x32x16_bf16(                \
            A[kc][rb], B[kc][1], acc[rb][1], 0, 0, 0);                       \
      }                                                                      \
  }

  // prologue: half 0 = (F0,CC0)
  LOADA(0, 0, aC);
  LOADB(0, 0, bC);

  // half h: CC = h/9, F = h%9 (cc-major). Counters avoid runtime div.
  int fN = 1, ccN = 0;   // coords of next N-group load (h = 2i+1)
  int fC = 2, ccC = 0;   // coords of next C-group refill (h = 2i+2)
  for (int i = 0; i < 36; ++i) {
    LOADA(fN, ccN, aN); LOADB(fN, ccN, bN);
    fN += 2; if (fN >= 9) { fN -= 9; ++ccN; }
    MFMA8(aC, bC);
    if (i < 35) {
      LOADA(fC, ccC, aC); LOADB(fC, ccC, bC);
      fC += 2; if (fC >= 9) { fC -= 9; ++ccC; }
    }
    MFMA8(aN, bN);
  }
#undef LOADA
#undef LOADB
#undef MFMA8

  // ---- per-channel partial sums -> atomics (C col = lane&31)
#pragma unroll
  for (int cb = 0; cb < 2; ++cb) {
    float s = 0.f, q = 0.f;
#pragma unroll
    for (int rb = 0; rb < 4; ++rb)
#pragma unroll
      for (int j = 0; j < 16; ++j) {
        float v = acc[rb][cb][j];
        s += v; q += v * v;
      }
    s += __shfl_xor(s, 32, 64);
    q += __shfl_xor(q, 32, 64);
    if (lh == 0) {
      int col = (w << 6) + cb * 32 + l31;
      atomicAdd(&stats[col], s);
      atomicAdd(&stats[256 + col], q);
    }
  }

  // ---- store y bf16: row = (reg&3) + 8*(reg>>2) + 4*lh, col = lane&31
  const long rbase = (long)gm * 128;
#pragma unroll
  for (int rb = 0; rb < 4; ++rb)
#pragma unroll
    for (int j = 0; j < 16; ++j) {
      long rr = rbase + rb * 32 + (j & 3) + 8 * (j >> 2) + 4 * lh;
      u16* dst = y + rr * 256 + (w << 6) + l31;
      dst[0]  = f32_bf16(acc[rb][0][j]);
      dst[32] = f32_bf16(acc[rb][1][j]);
    }
}

// ---- finalize BN coefficients: scale = gamma*rsqrt(var+eps), shift = beta - mean*scale
__global__ void bn_stats(const float* __restrict__ stats, const float* __restrict__ gamma,
                         const float* __restrict__ beta, float* __restrict__ sc) {
  int c = threadIdx.x;
  const float inv = 1.0f / (float)M_TOTAL;
  float mean = stats[c] * inv;
  float var  = stats[256 + c] * inv - mean * mean;
  float s = gamma[c] * rsqrtf(var + 1e-5f);
  float b = beta[c] - mean * s;
  sc[c] = s;
  sc[256 + c] = b;
}

// ---- fused BN + ReLU + 2x2 maxpool, NHWC bf16 -> NCHW f32 ----
__global__ void bn_pool(const u16* __restrict__ y, const float* __restrict__ sc,
                        float* __restrict__ out) {
  int b = blockIdx.x;                 // n*28 + ho
  int ho = b % 28, n = b / 28;
  __shared__ u16 t[256][113];         // [co][h2*56+wq], pad to break conflicts
  __shared__ float ssc[256], ssb[256];
  int tid = threadIdx.x;
  ssc[tid] = sc[tid];
  ssb[tid] = sc[256 + tid];
  const u16* src = y + (((long)n * 56 + ho * 2) * 56) * 256;
#pragma unroll
  for (int i = 0; i < 14; ++i) {
    int v = i * 256 + tid;            // vec idx over (h2,wq,co/8): 3584 vecs
    int cv = v & 31, hw = v >> 5;     // hw = h2*56+wq in 0..111
    union { uint4 u; u16 h[8]; } d;
    d.u = *(const uint4*)(src + (long)hw * 256 + cv * 8);
#pragma unroll
    for (int e = 0; e < 8; ++e) t[cv * 8 + e][hw] = d.h[e];
  }
  __syncthreads();
  float* dst = out + (long)n * 200704 + ho * 28;   // + co*784 + wo
#pragma unroll
  for (int i = 0; i < 28; ++i) {
    int oidx = i * 256 + tid;         // 0..7167
    int co = oidx / 28, wo = oidx - co * 28;
    float s = ssc[co], bb = ssb[co];
    int w0 = wo * 2;
    float r0 = fmaxf(s * bf16_f32(t[co][w0])      + bb, 0.f);
    float r1 = fmaxf(s * bf16_f32(t[co][w0 + 1])  + bb, 0.f);
    float r2 = fmaxf(s * bf16_f32(t[co][56 + w0]) + bb, 0.f);
    float r3 = fmaxf(s * bf16_f32(t[co][57 + w0]) + bb, 0.f);
    dst[(long)co * 784 + wo] = fmaxf(fmaxf(r0, r1), fmaxf(r2, r3));
  }
}

extern "C" void kernel_launch(void* const* d_in, const int* in_sizes, int n_in,
                              void* d_out, int out_size, void* d_ws, size_t ws_size,
                              hipStream_t stream) {
  const float* x     = (const float*)d_in[0];
  const float* W     = (const float*)d_in[1];
  const float* gamma = (const float*)d_in[2];
  const float* beta  = (const float*)d_in[3];
  float* out = (float*)d_out;
  char* ws = (char*)d_ws;
  u16*  xp2   = (u16*)ws;
  u16*  wp    = (u16*)(ws + WPACK_OFF);
  u16*  yb    = (u16*)(ws + Y_OFF);
  float* stats = (float*)(ws + STATS_OFF);   // sum[256], sumsq[256], scale[256], shift[256]

  hipMemsetAsync(stats, 0, 512 * sizeof(float), stream);
  hipLaunchKernelGGL(border_zero, dim3(912), dim3(256), 0, stream, xp2);
  hipLaunchKernelGGL(prep_w, dim3(2304), dim3(256), 0, stream, W, wp);
  hipLaunchKernelGGL(prep_x, dim3(32 * 56 * 4), dim3(256), 0, stream, x, xp2);
  hipLaunchKernelGGL(conv_gemm, dim3(784), dim3(256), 0, stream, xp2, wp, yb, stats);
  hipLaunchKernelGGL(bn_stats, dim3(1), dim3(256), 0, stream, stats, gamma, beta, stats + 512);
  hipLaunchKernelGGL(bn_pool, dim3(32 * 28), dim3(256), 0, stream, yb, stats + 512, out);
}